// Round 4
// baseline (3726.789 us; speedup 1.0000x reference)
//
#include <hip/hip_runtime.h>
#include <hip/hip_bf16.h>

typedef __bf16 bf16_t;
typedef __bf16 bf16x8 __attribute__((ext_vector_type(8)));
typedef float  floatx4 __attribute__((ext_vector_type(4)));

#define DIM    1024
#define S_LEN  2048
#define NHEAD  16

// ---------------------------------------------------------------------------
// GEMM: C(MxN) = A(MxK) @ B(KxN) + bias, optional ReLU / accumulate-into-C.
// ALL global tensors are f32 (per reference dtypes); A/B are converted to
// bf16 during LDS staging, MFMA accumulates f32 (2% abs threshold permits).
// B is in natural K-major layout; transposed into LDS [n][k] during staging.
// 128x128 tile, BK=32, 4 waves, 4x4 16x16x32 MFMA tiles per wave.
// Verified gfx950 layouts: A-frag A[m=lane&15][k=quad*8+i],
// B-frag Bs[n=lane&15][k=quad*8+i], C/D col=lane&15 row=quad*4+reg.
// ---------------------------------------------------------------------------
#define BM 128
#define BN 128
#define BK 32
#define LSTR 40  // 32 + 8 pad (bf16): 80B row stride (16B multiple), 2-way bank = free

__global__ __launch_bounds__(256) void gemm_bn(const float* __restrict__ A, int lda,
                                               const float* __restrict__ B, int ldb,
                                               float* C, int ldc,
                                               const float* __restrict__ bias,
                                               int K, int relu, int accum) {
  __shared__ bf16_t As[BM * LSTR];
  __shared__ bf16_t Bs[BN * LSTR];
  const int tid  = threadIdx.x;
  const int lane = tid & 63;
  const int wave = tid >> 6;
  const int wr   = wave >> 1;
  const int wc   = wave & 1;
  const int quad = lane >> 4;
  const int l15  = lane & 15;
  const int m0   = blockIdx.y * BM;
  const int n0   = blockIdx.x * BN;

  floatx4 acc[4][4];
#pragma unroll
  for (int i = 0; i < 4; ++i)
#pragma unroll
    for (int j = 0; j < 4; ++j) acc[i][j] = (floatx4)(0.0f);

  const int kIters = K / BK;
  for (int kt = 0; kt < kIters; ++kt) {
    // A tile 128x32: each id handles 8 consecutive k-floats (two float4 loads)
#pragma unroll
    for (int p = 0; p < 2; ++p) {
      int id  = p * 256 + tid;
      int row = id >> 2;
      int c8  = (id & 3) * 8;
      const float* src = A + (size_t)(m0 + row) * lda + kt * BK + c8;
      floatx4 f0 = *reinterpret_cast<const floatx4*>(src);
      floatx4 f1 = *reinterpret_cast<const floatx4*>(src + 4);
      bf16x8 hv;
      hv[0] = (bf16_t)f0[0]; hv[1] = (bf16_t)f0[1];
      hv[2] = (bf16_t)f0[2]; hv[3] = (bf16_t)f0[3];
      hv[4] = (bf16_t)f1[0]; hv[5] = (bf16_t)f1[1];
      hv[6] = (bf16_t)f1[2]; hv[7] = (bf16_t)f1[3];
      *reinterpret_cast<bf16x8*>(&As[row * LSTR + c8]) = hv;
    }
    // B tile 32(K) x 128(N): vector read along N, transposed scalar LDS writes
#pragma unroll
    for (int p = 0; p < 2; ++p) {
      int id  = p * 256 + tid;
      int kr  = id & 31;
      int nc8 = id >> 5;  // [0,16)
      const float* src = B + (size_t)(kt * BK + kr) * ldb + n0 + nc8 * 8;
      floatx4 f0 = *reinterpret_cast<const floatx4*>(src);
      floatx4 f1 = *reinterpret_cast<const floatx4*>(src + 4);
#pragma unroll
      for (int e = 0; e < 4; ++e) {
        Bs[(nc8 * 8 + e)     * LSTR + kr] = (bf16_t)f0[e];
        Bs[(nc8 * 8 + 4 + e) * LSTR + kr] = (bf16_t)f1[e];
      }
    }
    __syncthreads();

    bf16x8 a[4], b[4];
#pragma unroll
    for (int i = 0; i < 4; ++i)
      a[i] = *reinterpret_cast<const bf16x8*>(&As[(wr * 64 + i * 16 + l15) * LSTR + quad * 8]);
#pragma unroll
    for (int j = 0; j < 4; ++j)
      b[j] = *reinterpret_cast<const bf16x8*>(&Bs[(wc * 64 + j * 16 + l15) * LSTR + quad * 8]);
#pragma unroll
    for (int i = 0; i < 4; ++i)
#pragma unroll
      for (int j = 0; j < 4; ++j)
        acc[i][j] = __builtin_amdgcn_mfma_f32_16x16x32_bf16(a[i], b[j], acc[i][j], 0, 0, 0);
    __syncthreads();
  }

#pragma unroll
  for (int j = 0; j < 4; ++j) {
    int gn = n0 + wc * 64 + j * 16 + l15;
    float bv = bias ? bias[gn] : 0.0f;
#pragma unroll
    for (int i = 0; i < 4; ++i) {
      int gm = m0 + wr * 64 + i * 16 + quad * 4;
#pragma unroll
      for (int r = 0; r < 4; ++r) {
        float v = acc[i][j][r] + bv;
        if (relu) v = fmaxf(v, 0.0f);
        size_t idx = (size_t)(gm + r) * ldc + gn;
        if (accum) v += C[idx];
        C[idx] = v;
      }
    }
  }
}

// ---------------------------------------------------------------------------
// Flash attention (VALU, f32), causal, score scale 1/dph (reference quirk).
// PER-BATCH: qkv is one batch's 2048x3072 f32 strip; out its 2048x1024 strip.
// One workgroup = one head x 64-query tile. 256 thr: thread t owns q-row
// t>>2; sub-lane t&3 covers key-subset (scores) / 16-dim slice (PV).
// ---------------------------------------------------------------------------
#define QS 68

__device__ __forceinline__ void stage16f(float* dst, const float* src, float scale) {
#pragma unroll
  for (int i = 0; i < 4; ++i) {
    floatx4 f = *reinterpret_cast<const floatx4*>(src + i * 4);
    f *= scale;
    *reinterpret_cast<floatx4*>(dst + i * 4) = f;
  }
}

__global__ __launch_bounds__(256) void attn_k(const float* __restrict__ qkv,
                                              float* __restrict__ out) {
  __shared__ float Qs[64 * QS];
  __shared__ float KSs[64 * QS];  // K tile, then reused as score tile
  __shared__ float Vs[64 * QS];

  const int t   = threadIdx.x;
  const int qt  = blockIdx.x;
  const int h   = blockIdx.y;
  const int q0  = qt * 64;
  const int r   = t >> 2;
  const int sub = t & 3;
  const int db  = sub * 16;

  stage16f(&Qs[r * QS + db],
           qkv + (size_t)(q0 + r) * 3072 + h * 64 + db, 1.0f / 64.0f);

  float m_r = -1e30f, l_r = 0.0f;
  floatx4 O[4];
#pragma unroll
  for (int i = 0; i < 4; ++i) O[i] = (floatx4)(0.0f);

  for (int kt = 0; kt <= qt; ++kt) {
    __syncthreads();  // prior iter readers done (also covers Q staging, iter 0)
    {
      size_t kvBase = (size_t)(kt * 64 + r) * 3072 + h * 64 + db;
      stage16f(&KSs[r * QS + db], qkv + kvBase + 1024, 1.0f);
      stage16f(&Vs[r * QS + db],  qkv + kvBase + 2048, 1.0f);
    }
    __syncthreads();

    float sacc[16];
#pragma unroll
    for (int jj = 0; jj < 16; ++jj) sacc[jj] = 0.0f;
    for (int dc = 0; dc < 16; ++dc) {
      floatx4 q4 = *reinterpret_cast<const floatx4*>(&Qs[r * QS + dc * 4]);
#pragma unroll
      for (int jj = 0; jj < 16; ++jj) {
        int j = sub + 4 * jj;
        floatx4 k4 = *reinterpret_cast<const floatx4*>(&KSs[j * QS + dc * 4]);
        sacc[jj] += q4[0] * k4[0] + q4[1] * k4[1] + q4[2] * k4[2] + q4[3] * k4[3];
      }
    }
    __syncthreads();  // all K reads done before overwriting with scores

    const int gq = q0 + r;
#pragma unroll
    for (int jj = 0; jj < 16; ++jj) {
      int j  = sub + 4 * jj;
      int gk = kt * 64 + j;
      KSs[r * QS + j] = (gk > gq) ? -1e9f : sacc[jj];
    }
    __syncthreads();

    float mt = -1e30f;
    for (int j = 0; j < 64; ++j) mt = fmaxf(mt, KSs[r * QS + j]);
    float mnew  = fmaxf(m_r, mt);
    float alpha = __expf(m_r - mnew);
    l_r *= alpha;
#pragma unroll
    for (int i = 0; i < 4; ++i) O[i] *= alpha;
    for (int j = 0; j < 64; ++j) {
      float p = __expf(KSs[r * QS + j] - mnew);
      l_r += p;
#pragma unroll
      for (int dc = 0; dc < 4; ++dc) {
        floatx4 v4 = *reinterpret_cast<const floatx4*>(&Vs[j * QS + db + dc * 4]);
        O[dc] += p * v4;
      }
    }
    m_r = mnew;
  }

  const float inv = 1.0f / l_r;
  float* op = out + (size_t)(q0 + r) * DIM + h * 64 + db;
#pragma unroll
  for (int dc = 0; dc < 4; ++dc)
#pragma unroll
    for (int i = 0; i < 4; ++i)
      op[dc * 4 + i] = O[dc][i] * inv;
}

// ---------------------------------------------------------------------------
// out = LayerNorm(a + b) * g + beta  (row = 1024, eps 1e-5), all f32.
// May be called with out aliasing a or b (in-place): each thread reads only
// the elements it later writes — no cross-thread hazard.
// ---------------------------------------------------------------------------
__global__ __launch_bounds__(256) void add_ln_k(const float* a,
                                                const float* b,
                                                const float* __restrict__ g,
                                                const float* __restrict__ be,
                                                float* out) {
  const int row = blockIdx.x;
  const int t   = threadIdx.x;
  const size_t base = (size_t)row * DIM;

  floatx4 av = *reinterpret_cast<const floatx4*>(a + base + t * 4);
  floatx4 bv = *reinterpret_cast<const floatx4*>(b + base + t * 4);
  float x[4];
  float s1 = 0.0f, s2 = 0.0f;
#pragma unroll
  for (int i = 0; i < 4; ++i) {
    x[i] = av[i] + bv[i];
    s1 += x[i];
    s2 += x[i] * x[i];
  }
#pragma unroll
  for (int off = 32; off; off >>= 1) {
    s1 += __shfl_xor(s1, off);
    s2 += __shfl_xor(s2, off);
  }
  __shared__ float ls1[4], ls2[4];
  if ((t & 63) == 0) { ls1[t >> 6] = s1; ls2[t >> 6] = s2; }
  __syncthreads();
  float S1 = ls1[0] + ls1[1] + ls1[2] + ls1[3];
  float S2 = ls2[0] + ls2[1] + ls2[2] + ls2[3];
  float mu  = S1 * (1.0f / DIM);
  float var = S2 * (1.0f / DIM) - mu * mu;
  float rs  = rsqrtf(var + 1e-5f);
#pragma unroll
  for (int i = 0; i < 4; ++i) {
    int c = t * 4 + i;
    out[base + c] = (x[i] - mu) * rs * g[c] + be[c];
  }
}

// ---------------------------------------------------------------------------
extern "C" void kernel_launch(void* const* d_in, const int* in_sizes, int n_in,
                              void* d_out, int out_size, void* d_ws, size_t ws_size,
                              hipStream_t stream) {
  const float* x   = (const float*)d_in[0];
  const float* Wq  = (const float*)d_in[1];
  const float* Wk  = (const float*)d_in[2];
  const float* Wv  = (const float*)d_in[3];
  const float* bq  = (const float*)d_in[4];
  const float* bk  = (const float*)d_in[5];
  const float* bv  = (const float*)d_in[6];
  const float* g1  = (const float*)d_in[7];
  const float* be1 = (const float*)d_in[8];
  const float* W1  = (const float*)d_in[9];
  const float* b1  = (const float*)d_in[10];
  const float* W2  = (const float*)d_in[11];
  const float* b2  = (const float*)d_in[12];
  const float* g2  = (const float*)d_in[13];
  const float* be2 = (const float*)d_in[14];
  float* out = (float*)d_out;
  float* ws  = (float*)d_ws;

  // Per-batch pipeline. ws peak = 6,291,456 f32 = 25.2 MB:
  //   qkv_b [0, 6291456)           2048 x 3072 f32, live until attention done
  //   mid_h [0, 4194304)           2048 x 2048 f32, overlays dead qkv_b
  //   ffnO  [4194304, 6291456)     2048 x 1024 f32, overlays dead qkv_b
  // h lives in the batch's d_out strip (in-place add+LN).
  float* qkv  = ws;
  float* mid  = ws;
  float* ffnO = ws + 4194304;

  for (int b = 0; b < 4; ++b) {
    const float* xb   = x   + (size_t)b * S_LEN * DIM;
    float*       outb = out + (size_t)b * S_LEN * DIM;

    // QKV projections into strided qkv columns (M=2048, N=1024, K=1024)
    gemm_bn<<<dim3(8, 16), 256, 0, stream>>>(xb, 1024, Wq, 1024, qkv,        3072, bq, 1024, 0, 0);
    gemm_bn<<<dim3(8, 16), 256, 0, stream>>>(xb, 1024, Wk, 1024, qkv + 1024, 3072, bk, 1024, 0, 0);
    gemm_bn<<<dim3(8, 16), 256, 0, stream>>>(xb, 1024, Wv, 1024, qkv + 2048, 3072, bv, 1024, 0, 0);

    // attention -> outb, then h = LN(attn + x) in place
    attn_k<<<dim3(32, 16), 256, 0, stream>>>(qkv, outb);
    add_ln_k<<<2048, 256, 0, stream>>>(outb, xb, g1, be1, outb);

    // FFN in two hidden-dim halves (mid 2048x2048 reuses dead qkv space)
    gemm_bn<<<dim3(16, 16), 256, 0, stream>>>(outb, 1024, W1, 4096, mid, 2048, b1, 1024, 1, 0);
    gemm_bn<<<dim3(8, 16),  256, 0, stream>>>(mid, 2048, W2, 1024, ffnO, 1024, b2, 2048, 0, 0);
    gemm_bn<<<dim3(16, 16), 256, 0, stream>>>(outb, 1024, W1 + 2048, 4096, mid, 2048, b1 + 2048, 1024, 1, 0);
    gemm_bn<<<dim3(8, 16),  256, 0, stream>>>(mid, 2048, W2 + (size_t)2048 * 1024, 1024, ffnO, 1024, nullptr, 2048, 0, 1);

    // out = LN(ffn + h), in place
    add_ln_k<<<2048, 256, 0, stream>>>(ffnO, outb, g2, be2, outb);
  }
}

// Round 5
// 1124.074 us; speedup vs baseline: 3.3154x; 3.3154x over previous
//
#include <hip/hip_runtime.h>
#include <hip/hip_bf16.h>

typedef __bf16 bf16_t;
typedef __bf16 bf16x8 __attribute__((ext_vector_type(8)));
typedef __bf16 bf16x4 __attribute__((ext_vector_type(4)));
typedef float  floatx4 __attribute__((ext_vector_type(4)));

#define DIM    1024
#define S_LEN  2048
#define NHEAD  16

// ---------------------------------------------------------------------------
// load 8 consecutive elements as bf16x8 (f32 source converts, bf16 is a copy)
// ---------------------------------------------------------------------------
template <typename T>
__device__ __forceinline__ bf16x8 load8bf(const T* src) {
  if constexpr (sizeof(T) == 2) {
    return *reinterpret_cast<const bf16x8*>(src);
  } else {
    floatx4 f0 = *reinterpret_cast<const floatx4*>(src);
    floatx4 f1 = *reinterpret_cast<const floatx4*>(src + 4);
    bf16x8 h;
    h[0] = (bf16_t)f0[0]; h[1] = (bf16_t)f0[1];
    h[2] = (bf16_t)f0[2]; h[3] = (bf16_t)f0[3];
    h[4] = (bf16_t)f1[0]; h[5] = (bf16_t)f1[1];
    h[6] = (bf16_t)f1[2]; h[7] = (bf16_t)f1[3];
    return h;
  }
}

// ---------------------------------------------------------------------------
// GEMM: C(MxN) = A(MxK) @ B(KxN) + bias, optional ReLU. Generic in/out types
// (f32 or bf16); MFMA bf16 compute, f32 accumulate. blockIdx.z selects among
// {B0,B1,B2}/{bias0..2} and offsets C by z*zColOff (QKV fusion; z-grid=1 else).
// 128x128 tile, BK=32, 4 waves, 4x4 16x16x32 MFMA per wave.
// Verified gfx950 layouts: A-frag A[m=lane&15][k=quad*8+i],
// B-frag Bs[n=lane&15][k=quad*8+i], C/D col=lane&15 row=quad*4+reg.
// ---------------------------------------------------------------------------
#define BM 128
#define BN 128
#define BK 32
#define LSTR 40  // 32+8 pad: 80B row stride (16B multiple), 2-way bank = free

template <typename TA, typename TB, typename TC>
__global__ __launch_bounds__(256) void gemm_tn(
    const TA* __restrict__ A, int lda,
    const TB* __restrict__ B0, const TB* __restrict__ B1,
    const TB* __restrict__ B2, int ldb,
    TC* __restrict__ C, int ldc, int zColOff,
    const float* __restrict__ bias0, const float* __restrict__ bias1,
    const float* __restrict__ bias2,
    int K, int relu) {
  __shared__ bf16_t As[BM * LSTR];
  __shared__ bf16_t Bs[BN * LSTR];
  const int z = blockIdx.z;
  const TB* B = (z == 0) ? B0 : ((z == 1) ? B1 : B2);
  const float* bias = (z == 0) ? bias0 : ((z == 1) ? bias1 : bias2);
  C += (size_t)z * zColOff;

  const int tid  = threadIdx.x;
  const int lane = tid & 63;
  const int wave = tid >> 6;
  const int wr   = wave >> 1;
  const int wc   = wave & 1;
  const int quad = lane >> 4;
  const int l15  = lane & 15;
  const int m0   = blockIdx.y * BM;
  const int n0   = blockIdx.x * BN;

  floatx4 acc[4][4];
#pragma unroll
  for (int i = 0; i < 4; ++i)
#pragma unroll
    for (int j = 0; j < 4; ++j) acc[i][j] = (floatx4)(0.0f);

  const int kIters = K / BK;
  for (int kt = 0; kt < kIters; ++kt) {
#pragma unroll
    for (int p = 0; p < 2; ++p) {
      int id  = p * 256 + tid;
      int row = id >> 2;
      int c8  = (id & 3) * 8;
      bf16x8 hv = load8bf(A + (size_t)(m0 + row) * lda + kt * BK + c8);
      *reinterpret_cast<bf16x8*>(&As[row * LSTR + c8]) = hv;
    }
#pragma unroll
    for (int p = 0; p < 2; ++p) {
      int id  = p * 256 + tid;
      int kr  = id & 31;
      int nc8 = id >> 5;
      bf16x8 hv = load8bf(B + (size_t)(kt * BK + kr) * ldb + n0 + nc8 * 8);
#pragma unroll
      for (int e = 0; e < 8; ++e)
        Bs[(nc8 * 8 + e) * LSTR + kr] = hv[e];
    }
    __syncthreads();

    bf16x8 a[4], b[4];
#pragma unroll
    for (int i = 0; i < 4; ++i)
      a[i] = *reinterpret_cast<const bf16x8*>(&As[(wr * 64 + i * 16 + l15) * LSTR + quad * 8]);
#pragma unroll
    for (int j = 0; j < 4; ++j)
      b[j] = *reinterpret_cast<const bf16x8*>(&Bs[(wc * 64 + j * 16 + l15) * LSTR + quad * 8]);
#pragma unroll
    for (int i = 0; i < 4; ++i)
#pragma unroll
      for (int j = 0; j < 4; ++j)
        acc[i][j] = __builtin_amdgcn_mfma_f32_16x16x32_bf16(a[i], b[j], acc[i][j], 0, 0, 0);
    __syncthreads();
  }

#pragma unroll
  for (int j = 0; j < 4; ++j) {
    int gn = n0 + wc * 64 + j * 16 + l15;
    float bv = bias[gn];
#pragma unroll
    for (int i = 0; i < 4; ++i) {
      int gm = m0 + wr * 64 + i * 16 + quad * 4;
#pragma unroll
      for (int r = 0; r < 4; ++r) {
        float v = acc[i][j][r] + bv;
        if (relu) v = fmaxf(v, 0.0f);
        C[(size_t)(gm + r) * ldc + gn] = (TC)v;
      }
    }
  }
}

// ---------------------------------------------------------------------------
// V transpose: per (pair-local batch z, head h), V slice [2048 s][64 d] from
// qkv2 (col offset 2048+h*64, row stride 3072) -> vt[bh][64 d][2048 s].
// ---------------------------------------------------------------------------
__global__ __launch_bounds__(256) void transpose_v(const bf16_t* __restrict__ in,
                                                   bf16_t* __restrict__ outp) {
  __shared__ bf16_t tile[32][33];
  int tx = threadIdx.x, ty = threadIdx.y;
  int s0 = blockIdx.x * 32, d0 = blockIdx.y * 32, bh = blockIdx.z;
  int z = bh >> 4, h = bh & 15;
  const bf16_t* src = in + (size_t)z * S_LEN * 3072 + 2048 + h * 64;
#pragma unroll
  for (int i = 0; i < 4; ++i)
    tile[ty + 8 * i][tx] = src[(size_t)(s0 + ty + 8 * i) * 3072 + d0 + tx];
  __syncthreads();
  bf16_t* dst = outp + (size_t)bh * 64 * S_LEN;
#pragma unroll
  for (int i = 0; i < 4; ++i)
    dst[(size_t)(d0 + ty + 8 * i) * S_LEN + s0 + tx] = tile[tx][ty + 8 * i];
}

// ---------------------------------------------------------------------------
// MFMA flash attention, causal, scale 1/dph folded into Q staging (1/64,
// pow2 -> exact in bf16). One workgroup = 128 queries x one (z,h).
// 4 waves x 32 q-rows. K-tiles of 64 keys. Q/K natural [s][64] layouts ARE
// the MFMA A/B fragment layouts (k = dph = 64 = 2 x K32). P round-trips
// through LDS (within-wave: no barrier needed). V read pre-transposed (vt).
// Online softmax in C-layout regs; row stats via 16-lane shuffle reduce.
// ---------------------------------------------------------------------------
#define TQ  128
#define TK  64
#define AST 72  // LDS row stride bf16: 144B (16B mult), b128 reads 2-way = free

__global__ __launch_bounds__(256) void attn_mfma(const bf16_t* __restrict__ qkv,
                                                 const bf16_t* __restrict__ vt,
                                                 float* __restrict__ out) {
  __shared__ bf16_t Qs[TQ * AST];
  __shared__ bf16_t Ks[TK * AST];
  __shared__ bf16_t Vs[TK * AST];  // V^T tile: [d][key]
  __shared__ bf16_t Ps[TQ * AST];

  const int tid  = threadIdx.x;
  const int lane = tid & 63;
  const int w    = tid >> 6;
  const int quad = lane >> 4;
  const int l15  = lane & 15;
  const int qb   = blockIdx.x;
  const int h    = blockIdx.y;
  const int z    = blockIdx.z;
  const bf16_t* qkv_b = qkv + (size_t)z * S_LEN * 3072;
  const bf16_t* vt_bh = vt + ((size_t)z * NHEAD + h) * 64 * S_LEN;
  float* out_b = out + (size_t)z * S_LEN * DIM;
  const int qg0 = qb * TQ;

  // stage Q (scaled 1/64): 128x64, 1024 16B-chunks, 4/thread
#pragma unroll
  for (int p = 0; p < 4; ++p) {
    int id  = p * 256 + tid;
    int row = id >> 3;
    int c8  = (id & 7) * 8;
    bf16x8 v = *reinterpret_cast<const bf16x8*>(
        qkv_b + (size_t)(qg0 + row) * 3072 + h * 64 + c8);
    bf16x8 o;
#pragma unroll
    for (int e = 0; e < 8; ++e) o[e] = (bf16_t)((float)v[e] * 0.015625f);
    *reinterpret_cast<bf16x8*>(&Qs[row * AST + c8]) = o;
  }
  __syncthreads();

  // per-wave Q fragments (constant over the K loop)
  bf16x8 aq[2][2];
#pragma unroll
  for (int qt = 0; qt < 2; ++qt)
#pragma unroll
    for (int ks = 0; ks < 2; ++ks)
      aq[qt][ks] = *reinterpret_cast<const bf16x8*>(
          &Qs[(w * 32 + qt * 16 + l15) * AST + ks * 32 + quad * 8]);

  float m_run[2][4], l_run[2][4];
  floatx4 O[2][4];
#pragma unroll
  for (int qt = 0; qt < 2; ++qt)
#pragma unroll
    for (int r = 0; r < 4; ++r) { m_run[qt][r] = -1e30f; l_run[qt][r] = 0.0f; }
#pragma unroll
  for (int qt = 0; qt < 2; ++qt)
#pragma unroll
    for (int dt = 0; dt < 4; ++dt) O[qt][dt] = (floatx4)(0.0f);

  const int ktEnd = 2 * (qb + 1);  // key tiles covering [0, qg0+128)
  for (int kt = 0; kt < ktEnd; ++kt) {
    __syncthreads();  // prior-iter K/V readers done
    // stage K tile [key][d] and V^T tile [d][key]: 512 chunks each, 2/thread
#pragma unroll
    for (int p = 0; p < 2; ++p) {
      int id  = p * 256 + tid;
      int row = id >> 3;
      int c8  = (id & 7) * 8;
      *reinterpret_cast<bf16x8*>(&Ks[row * AST + c8]) =
          *reinterpret_cast<const bf16x8*>(
              qkv_b + (size_t)(kt * TK + row) * 3072 + 1024 + h * 64 + c8);
      *reinterpret_cast<bf16x8*>(&Vs[row * AST + c8]) =
          *reinterpret_cast<const bf16x8*>(
              vt_bh + (size_t)row * S_LEN + kt * TK + c8);
    }
    __syncthreads();

    // V^T B-fragments (shared across qt)
    bf16x8 bv[4][2];
#pragma unroll
    for (int dt = 0; dt < 4; ++dt)
#pragma unroll
      for (int ks = 0; ks < 2; ++ks)
        bv[dt][ks] = *reinterpret_cast<const bf16x8*>(
            &Vs[(dt * 16 + l15) * AST + ks * 32 + quad * 8]);

#pragma unroll
    for (int qt = 0; qt < 2; ++qt) {
      const int qtb = qg0 + w * 32 + qt * 16;  // qtile base row
      if (kt * TK > qtb + 15) continue;        // fully above diagonal: skip

      // S = Q K^T (32x64 per wave-qtile pair -> this qtile: 16x64)
      floatx4 s[4];
#pragma unroll
      for (int ktl = 0; ktl < 4; ++ktl) {
        bf16x8 bk0 = *reinterpret_cast<const bf16x8*>(
            &Ks[(ktl * 16 + l15) * AST + quad * 8]);
        bf16x8 bk1 = *reinterpret_cast<const bf16x8*>(
            &Ks[(ktl * 16 + l15) * AST + 32 + quad * 8]);
        s[ktl] = __builtin_amdgcn_mfma_f32_16x16x32_bf16(aq[qt][0], bk0,
                                                         (floatx4)(0.0f), 0, 0, 0);
        s[ktl] = __builtin_amdgcn_mfma_f32_16x16x32_bf16(aq[qt][1], bk1,
                                                         s[ktl], 0, 0, 0);
      }
      // causal mask (only if tile straddles the diagonal)
      if (kt * TK + TK - 1 > qtb) {
#pragma unroll
        for (int ktl = 0; ktl < 4; ++ktl) {
          int gk = kt * TK + ktl * 16 + l15;
#pragma unroll
          for (int r = 0; r < 4; ++r) {
            int gq = qtb + quad * 4 + r;
            if (gk > gq) s[ktl][r] = -1e30f;
          }
        }
      }
      // online softmax (row stats: reduce across the 16 col-lanes)
      float mrow[4], lsum[4], alpha[4];
#pragma unroll
      for (int r = 0; r < 4; ++r) {
        float mv = fmaxf(fmaxf(s[0][r], s[1][r]), fmaxf(s[2][r], s[3][r]));
#pragma unroll
        for (int off = 1; off < 16; off <<= 1)
          mv = fmaxf(mv, __shfl_xor(mv, off));
        float mn = fmaxf(m_run[qt][r], mv);
        alpha[r] = __expf(m_run[qt][r] - mn);
        m_run[qt][r] = mn;
        lsum[r] = 0.0f;
      }
#pragma unroll
      for (int ktl = 0; ktl < 4; ++ktl)
#pragma unroll
        for (int r = 0; r < 4; ++r) {
          float p = __expf(s[ktl][r] - m_run[qt][r]);
          s[ktl][r] = p;
          lsum[r] += p;
        }
#pragma unroll
      for (int r = 0; r < 4; ++r) {
#pragma unroll
        for (int off = 1; off < 16; off <<= 1)
          lsum[r] += __shfl_xor(lsum[r], off);
        l_run[qt][r] = l_run[qt][r] * alpha[r] + lsum[r];
      }
      // rescale O, write P (bf16) to LDS in C-layout position
#pragma unroll
      for (int dt = 0; dt < 4; ++dt)
#pragma unroll
        for (int r = 0; r < 4; ++r) O[qt][dt][r] *= alpha[r];
#pragma unroll
      for (int ktl = 0; ktl < 4; ++ktl)
#pragma unroll
        for (int r = 0; r < 4; ++r)
          Ps[(w * 32 + qt * 16 + quad * 4 + r) * AST + ktl * 16 + l15] =
              (bf16_t)s[ktl][r];

      // PV: A = P (own rows; within-wave LDS dep, compiler waitcnt)
      bf16x8 ap0 = *reinterpret_cast<const bf16x8*>(
          &Ps[(w * 32 + qt * 16 + l15) * AST + quad * 8]);
      bf16x8 ap1 = *reinterpret_cast<const bf16x8*>(
          &Ps[(w * 32 + qt * 16 + l15) * AST + 32 + quad * 8]);
#pragma unroll
      for (int dt = 0; dt < 4; ++dt) {
        O[qt][dt] = __builtin_amdgcn_mfma_f32_16x16x32_bf16(ap0, bv[dt][0],
                                                            O[qt][dt], 0, 0, 0);
        O[qt][dt] = __builtin_amdgcn_mfma_f32_16x16x32_bf16(ap1, bv[dt][1],
                                                            O[qt][dt], 0, 0, 0);
      }
    }
  }

  // epilogue: O / l -> out (f32)
#pragma unroll
  for (int qt = 0; qt < 2; ++qt) {
    float inv[4];
#pragma unroll
    for (int r = 0; r < 4; ++r) inv[r] = 1.0f / l_run[qt][r];
#pragma unroll
    for (int dt = 0; dt < 4; ++dt)
#pragma unroll
      for (int r = 0; r < 4; ++r)
        out_b[(size_t)(qg0 + w * 32 + qt * 16 + quad * 4 + r) * DIM +
              h * 64 + dt * 16 + l15] = O[qt][dt][r] * inv[r];
  }
}

// ---------------------------------------------------------------------------
// out = LayerNorm(a + b) * g + beta (row = 1024, eps 1e-5). a generic dtype.
// Alias-safe in place (per-thread read-before-write).
// ---------------------------------------------------------------------------
template <typename TA>
__global__ __launch_bounds__(256) void add_ln_k(const TA* a,
                                                const float* b,
                                                const float* __restrict__ g,
                                                const float* __restrict__ be,
                                                float* out) {
  const int row = blockIdx.x;
  const int t   = threadIdx.x;
  const size_t base = (size_t)row * DIM;

  float x[4];
  {
    floatx4 bv = *reinterpret_cast<const floatx4*>(b + base + t * 4);
    if constexpr (sizeof(TA) == 2) {
      bf16x4 av = *reinterpret_cast<const bf16x4*>(a + base + t * 4);
#pragma unroll
      for (int i = 0; i < 4; ++i) x[i] = (float)av[i] + bv[i];
    } else {
      floatx4 av = *reinterpret_cast<const floatx4*>(a + base + t * 4);
#pragma unroll
      for (int i = 0; i < 4; ++i) x[i] = av[i] + bv[i];
    }
  }
  float s1 = 0.0f, s2 = 0.0f;
#pragma unroll
  for (int i = 0; i < 4; ++i) { s1 += x[i]; s2 += x[i] * x[i]; }
#pragma unroll
  for (int off = 32; off; off >>= 1) {
    s1 += __shfl_xor(s1, off);
    s2 += __shfl_xor(s2, off);
  }
  __shared__ float ls1[4], ls2[4];
  if ((t & 63) == 0) { ls1[t >> 6] = s1; ls2[t >> 6] = s2; }
  __syncthreads();
  float S1 = ls1[0] + ls1[1] + ls1[2] + ls1[3];
  float S2 = ls2[0] + ls2[1] + ls2[2] + ls2[3];
  float mu  = S1 * (1.0f / DIM);
  float var = S2 * (1.0f / DIM) - mu * mu;
  float rs  = rsqrtf(var + 1e-5f);
#pragma unroll
  for (int i = 0; i < 4; ++i) {
    int c = t * 4 + i;
    out[base + c] = (x[i] - mu) * rs * g[c] + be[c];
  }
}

// ---------------------------------------------------------------------------
extern "C" void kernel_launch(void* const* d_in, const int* in_sizes, int n_in,
                              void* d_out, int out_size, void* d_ws, size_t ws_size,
                              hipStream_t stream) {
  const float* x   = (const float*)d_in[0];
  const float* Wq  = (const float*)d_in[1];
  const float* Wk  = (const float*)d_in[2];
  const float* Wv  = (const float*)d_in[3];
  const float* bq  = (const float*)d_in[4];
  const float* bk  = (const float*)d_in[5];
  const float* bv  = (const float*)d_in[6];
  const float* g1  = (const float*)d_in[7];
  const float* be1 = (const float*)d_in[8];
  const float* W1  = (const float*)d_in[9];
  const float* b1  = (const float*)d_in[10];
  const float* W2  = (const float*)d_in[11];
  const float* b2  = (const float*)d_in[12];
  const float* g2  = (const float*)d_in[13];
  const float* be2 = (const float*)d_in[14];
  float* out = (float*)d_out;
  char*  ws  = (char*)d_ws;

  // ws layout (bytes), peak 40 MiB (<= 48 MiB proven safe in R2):
  //   phase 1 (per batch-pair): qkv2 [0, 25165824)  4096x3072 bf16
  //                             vt   [25165824, 33554432)  32 x 64 x 2048 bf16
  //   phase 2 (per M-half):     mid  [0, 33554432)  4096x4096 bf16
  //                             ffnO [33554432, 41943040)  4096x1024 bf16
  bf16_t* qkv2 = (bf16_t*)(ws);
  bf16_t* vt   = (bf16_t*)(ws + 25165824);
  bf16_t* mid  = (bf16_t*)(ws);
  bf16_t* ffnO = (bf16_t*)(ws + 33554432);

  // --- QKV + attention, per batch-pair ---
  for (int p = 0; p < 2; ++p) {
    const float* xp   = x   + (size_t)p * 2 * S_LEN * DIM;
    float*       outp = out + (size_t)p * 2 * S_LEN * DIM;
    gemm_tn<float, float, bf16_t><<<dim3(8, 32, 3), 256, 0, stream>>>(
        xp, 1024, Wq, Wk, Wv, 1024, qkv2, 3072, 1024, bq, bk, bv, 1024, 0);
    transpose_v<<<dim3(64, 2, 32), dim3(32, 8), 0, stream>>>(qkv2, vt);
    attn_mfma<<<dim3(16, 16, 2), 256, 0, stream>>>(qkv2, vt, outp);
  }
  // h = LN(attn + x), in place in d_out
  add_ln_k<float><<<8192, 256, 0, stream>>>(out, x, g1, be1, out);

  // --- FFN per M-half (mid = full hidden 4096, single-pass FFN2) ---
  for (int m = 0; m < 2; ++m) {
    float* hm = out + (size_t)m * 4096 * DIM;
    gemm_tn<float, float, bf16_t><<<dim3(32, 32, 1), 256, 0, stream>>>(
        hm, 1024, W1, W1, W1, 4096, mid, 4096, 0, b1, b1, b1, 1024, 1);
    gemm_tn<bf16_t, float, bf16_t><<<dim3(8, 32, 1), 256, 0, stream>>>(
        mid, 4096, W2, W2, W2, 1024, ffnO, 1024, 0, b2, b2, b2, 4096, 0);
    add_ln_k<bf16_t><<<4096, 256, 0, stream>>>(ffnO, hm, g2, be2, hm);
  }
}

// Round 6
// 868.321 us; speedup vs baseline: 4.2920x; 1.2945x over previous
//
#include <hip/hip_runtime.h>
#include <hip/hip_bf16.h>

typedef __bf16 bf16_t;
typedef __bf16 bf16x8 __attribute__((ext_vector_type(8)));
typedef __bf16 bf16x4 __attribute__((ext_vector_type(4)));
typedef float  floatx4 __attribute__((ext_vector_type(4)));

#define DIM    1024
#define S_LEN  2048
#define NHEAD  16

// ---------------------------------------------------------------------------
// load 8 consecutive elements as bf16x8 (f32 source converts, bf16 is a copy)
// ---------------------------------------------------------------------------
template <typename T>
__device__ __forceinline__ bf16x8 load8bf(const T* src) {
  if constexpr (sizeof(T) == 2) {
    return *reinterpret_cast<const bf16x8*>(src);
  } else {
    floatx4 f0 = *reinterpret_cast<const floatx4*>(src);
    floatx4 f1 = *reinterpret_cast<const floatx4*>(src + 4);
    bf16x8 h;
    h[0] = (bf16_t)f0[0]; h[1] = (bf16_t)f0[1];
    h[2] = (bf16_t)f0[2]; h[3] = (bf16_t)f0[3];
    h[4] = (bf16_t)f1[0]; h[5] = (bf16_t)f1[1];
    h[6] = (bf16_t)f1[2]; h[7] = (bf16_t)f1[3];
    return h;
  }
}

// ---------------------------------------------------------------------------
// Weight transpose+convert: in f32 (K x N slice, row stride ldi) ->
// out bf16 (N x K, row stride ldo). 32x32 tiles, block (32,8).
// ---------------------------------------------------------------------------
__global__ __launch_bounds__(256) void convT(const float* __restrict__ in, int ldi,
                                             bf16_t* __restrict__ out, int ldo) {
  __shared__ bf16_t tile[32][33];
  int tx = threadIdx.x, ty = threadIdx.y;
  int n0 = blockIdx.x * 32, k0 = blockIdx.y * 32;
#pragma unroll
  for (int i = 0; i < 4; ++i)
    tile[ty + 8 * i][tx] = (bf16_t)in[(size_t)(k0 + ty + 8 * i) * ldi + n0 + tx];
  __syncthreads();
#pragma unroll
  for (int i = 0; i < 4; ++i)
    out[(size_t)(n0 + ty + 8 * i) * ldo + k0 + tx] = tile[tx][ty + 8 * i];
}

// ---------------------------------------------------------------------------
// GEMM: C(MxN) = A(MxK) @ Bt(NxK)^T + bias; optional ReLU / bf16-accumulate.
// A f32 or bf16 (converted during staging); Bt is pre-transposed bf16 with
// contiguous K (ldbt = K) -> B staging is identical vectorized 16B row loads.
// blockIdx.z: Bt row offset z*zBRow, C col offset z*zCOff, bias selection
// (QKV fusion; z-grid=1 otherwise). 128x128 tile, BK=32, 4 waves, 4x4 MFMA.
// Verified gfx950 layouts: A-frag A[m=lane&15][k=quad*8+i],
// B-frag Bs[n=lane&15][k=quad*8+i], C/D col=lane&15 row=quad*4+reg.
// ---------------------------------------------------------------------------
#define BM 128
#define BN 128
#define BK 32
#define LSTR 40  // 32+8 pad: 80B row stride (16B multiple), 2-way bank = free

template <typename TA>
__global__ __launch_bounds__(256) void gemm_abt(
    const TA* __restrict__ A, int lda,
    const bf16_t* __restrict__ Bt, int zBRow,
    bf16_t* __restrict__ C, int ldc, int zCOff,
    const float* __restrict__ bias0, const float* __restrict__ bias1,
    const float* __restrict__ bias2,
    int K, int relu, int accum) {
  __shared__ bf16_t As[BM * LSTR];
  __shared__ bf16_t Bs[BN * LSTR];
  const int z = blockIdx.z;
  const float* bias = (z == 0) ? bias0 : ((z == 1) ? bias1 : bias2);
  const bf16_t* Bz = Bt + (size_t)z * zBRow * K;
  C += (size_t)z * zCOff;

  const int tid  = threadIdx.x;
  const int lane = tid & 63;
  const int wave = tid >> 6;
  const int wr   = wave >> 1;
  const int wc   = wave & 1;
  const int quad = lane >> 4;
  const int l15  = lane & 15;
  const int m0   = blockIdx.y * BM;
  const int n0   = blockIdx.x * BN;

  floatx4 acc[4][4];
#pragma unroll
  for (int i = 0; i < 4; ++i)
#pragma unroll
    for (int j = 0; j < 4; ++j) acc[i][j] = (floatx4)(0.0f);

  const int kIters = K / BK;
  for (int kt = 0; kt < kIters; ++kt) {
#pragma unroll
    for (int p = 0; p < 2; ++p) {
      int id  = p * 256 + tid;
      int row = id >> 2;
      int c8  = (id & 3) * 8;
      *reinterpret_cast<bf16x8*>(&As[row * LSTR + c8]) =
          load8bf(A + (size_t)(m0 + row) * lda + kt * BK + c8);
      *reinterpret_cast<bf16x8*>(&Bs[row * LSTR + c8]) =
          *reinterpret_cast<const bf16x8*>(Bz + (size_t)(n0 + row) * K + kt * BK + c8);
    }
    __syncthreads();

    bf16x8 a[4], b[4];
#pragma unroll
    for (int i = 0; i < 4; ++i)
      a[i] = *reinterpret_cast<const bf16x8*>(&As[(wr * 64 + i * 16 + l15) * LSTR + quad * 8]);
#pragma unroll
    for (int j = 0; j < 4; ++j)
      b[j] = *reinterpret_cast<const bf16x8*>(&Bs[(wc * 64 + j * 16 + l15) * LSTR + quad * 8]);
#pragma unroll
    for (int i = 0; i < 4; ++i)
#pragma unroll
      for (int j = 0; j < 4; ++j)
        acc[i][j] = __builtin_amdgcn_mfma_f32_16x16x32_bf16(a[i], b[j], acc[i][j], 0, 0, 0);
    __syncthreads();
  }

#pragma unroll
  for (int j = 0; j < 4; ++j) {
    int gn = n0 + wc * 64 + j * 16 + l15;
    float bv = bias ? bias[gn] : 0.0f;
#pragma unroll
    for (int i = 0; i < 4; ++i) {
      int gm = m0 + wr * 64 + i * 16 + quad * 4;
#pragma unroll
      for (int r = 0; r < 4; ++r) {
        float v = acc[i][j][r] + bv;
        if (relu) v = fmaxf(v, 0.0f);
        size_t idx = (size_t)(gm + r) * ldc + gn;
        if (accum) v += (float)C[idx];
        C[idx] = (bf16_t)v;
      }
    }
  }
}

// ---------------------------------------------------------------------------
// V transpose: per (pair-local batch z, head h), V slice [2048 s][64 d] from
// qkv2 (col offset 2048+h*64, row stride 3072) -> vt[bh][64 d][2048 s].
// ---------------------------------------------------------------------------
__global__ __launch_bounds__(256) void transpose_v(const bf16_t* __restrict__ in,
                                                   bf16_t* __restrict__ outp) {
  __shared__ bf16_t tile[32][33];
  int tx = threadIdx.x, ty = threadIdx.y;
  int s0 = blockIdx.x * 32, d0 = blockIdx.y * 32, bh = blockIdx.z;
  int z = bh >> 4, h = bh & 15;
  const bf16_t* src = in + (size_t)z * S_LEN * 3072 + 2048 + h * 64;
#pragma unroll
  for (int i = 0; i < 4; ++i)
    tile[ty + 8 * i][tx] = src[(size_t)(s0 + ty + 8 * i) * 3072 + d0 + tx];
  __syncthreads();
  bf16_t* dst = outp + (size_t)bh * 64 * S_LEN;
#pragma unroll
  for (int i = 0; i < 4; ++i)
    dst[(size_t)(d0 + ty + 8 * i) * S_LEN + s0 + tx] = tile[tx][ty + 8 * i];
}

// ---------------------------------------------------------------------------
// MFMA flash attention, causal, scale 1/dph folded into Q staging (1/64).
// One workgroup = 128 queries x one (z,h). 4 waves x 32 q-rows. K-tiles of
// 64 keys. Q/K natural [s][64] layouts ARE the MFMA A/B fragment layouts.
// P round-trips through LDS (within-wave). V read pre-transposed (vt).
// ---------------------------------------------------------------------------
#define TQ  128
#define TK  64
#define AST 72  // LDS row stride bf16: 144B (16B mult), b128 reads 2-way = free

__global__ __launch_bounds__(256) void attn_mfma(const bf16_t* __restrict__ qkv,
                                                 const bf16_t* __restrict__ vt,
                                                 float* __restrict__ out) {
  __shared__ bf16_t Qs[TQ * AST];
  __shared__ bf16_t Ks[TK * AST];
  __shared__ bf16_t Vs[TK * AST];  // V^T tile: [d][key]
  __shared__ bf16_t Ps[TQ * AST];

  const int tid  = threadIdx.x;
  const int lane = tid & 63;
  const int w    = tid >> 6;
  const int quad = lane >> 4;
  const int l15  = lane & 15;
  const int qb   = blockIdx.x;
  const int h    = blockIdx.y;
  const int z    = blockIdx.z;
  const bf16_t* qkv_b = qkv + (size_t)z * S_LEN * 3072;
  const bf16_t* vt_bh = vt + ((size_t)z * NHEAD + h) * 64 * S_LEN;
  float* out_b = out + (size_t)z * S_LEN * DIM;
  const int qg0 = qb * TQ;

#pragma unroll
  for (int p = 0; p < 4; ++p) {
    int id  = p * 256 + tid;
    int row = id >> 3;
    int c8  = (id & 7) * 8;
    bf16x8 v = *reinterpret_cast<const bf16x8*>(
        qkv_b + (size_t)(qg0 + row) * 3072 + h * 64 + c8);
    bf16x8 o;
#pragma unroll
    for (int e = 0; e < 8; ++e) o[e] = (bf16_t)((float)v[e] * 0.015625f);
    *reinterpret_cast<bf16x8*>(&Qs[row * AST + c8]) = o;
  }
  __syncthreads();

  bf16x8 aq[2][2];
#pragma unroll
  for (int qt = 0; qt < 2; ++qt)
#pragma unroll
    for (int ks = 0; ks < 2; ++ks)
      aq[qt][ks] = *reinterpret_cast<const bf16x8*>(
          &Qs[(w * 32 + qt * 16 + l15) * AST + ks * 32 + quad * 8]);

  float m_run[2][4], l_run[2][4];
  floatx4 O[2][4];
#pragma unroll
  for (int qt = 0; qt < 2; ++qt)
#pragma unroll
    for (int r = 0; r < 4; ++r) { m_run[qt][r] = -1e30f; l_run[qt][r] = 0.0f; }
#pragma unroll
  for (int qt = 0; qt < 2; ++qt)
#pragma unroll
    for (int dt = 0; dt < 4; ++dt) O[qt][dt] = (floatx4)(0.0f);

  const int ktEnd = 2 * (qb + 1);
  for (int kt = 0; kt < ktEnd; ++kt) {
    __syncthreads();
#pragma unroll
    for (int p = 0; p < 2; ++p) {
      int id  = p * 256 + tid;
      int row = id >> 3;
      int c8  = (id & 7) * 8;
      *reinterpret_cast<bf16x8*>(&Ks[row * AST + c8]) =
          *reinterpret_cast<const bf16x8*>(
              qkv_b + (size_t)(kt * TK + row) * 3072 + 1024 + h * 64 + c8);
      *reinterpret_cast<bf16x8*>(&Vs[row * AST + c8]) =
          *reinterpret_cast<const bf16x8*>(
              vt_bh + (size_t)row * S_LEN + kt * TK + c8);
    }
    __syncthreads();

    bf16x8 bv[4][2];
#pragma unroll
    for (int dt = 0; dt < 4; ++dt)
#pragma unroll
      for (int ks = 0; ks < 2; ++ks)
        bv[dt][ks] = *reinterpret_cast<const bf16x8*>(
            &Vs[(dt * 16 + l15) * AST + ks * 32 + quad * 8]);

#pragma unroll
    for (int qt = 0; qt < 2; ++qt) {
      const int qtb = qg0 + w * 32 + qt * 16;
      if (kt * TK > qtb + 15) continue;

      floatx4 s[4];
#pragma unroll
      for (int ktl = 0; ktl < 4; ++ktl) {
        bf16x8 bk0 = *reinterpret_cast<const bf16x8*>(
            &Ks[(ktl * 16 + l15) * AST + quad * 8]);
        bf16x8 bk1 = *reinterpret_cast<const bf16x8*>(
            &Ks[(ktl * 16 + l15) * AST + 32 + quad * 8]);
        s[ktl] = __builtin_amdgcn_mfma_f32_16x16x32_bf16(aq[qt][0], bk0,
                                                         (floatx4)(0.0f), 0, 0, 0);
        s[ktl] = __builtin_amdgcn_mfma_f32_16x16x32_bf16(aq[qt][1], bk1,
                                                         s[ktl], 0, 0, 0);
      }
      if (kt * TK + TK - 1 > qtb) {
#pragma unroll
        for (int ktl = 0; ktl < 4; ++ktl) {
          int gk = kt * TK + ktl * 16 + l15;
#pragma unroll
          for (int r = 0; r < 4; ++r) {
            int gq = qtb + quad * 4 + r;
            if (gk > gq) s[ktl][r] = -1e30f;
          }
        }
      }
      float lsum[4], alpha[4];
#pragma unroll
      for (int r = 0; r < 4; ++r) {
        float mv = fmaxf(fmaxf(s[0][r], s[1][r]), fmaxf(s[2][r], s[3][r]));
#pragma unroll
        for (int off = 1; off < 16; off <<= 1)
          mv = fmaxf(mv, __shfl_xor(mv, off));
        float mn = fmaxf(m_run[qt][r], mv);
        alpha[r] = __expf(m_run[qt][r] - mn);
        m_run[qt][r] = mn;
        lsum[r] = 0.0f;
      }
#pragma unroll
      for (int ktl = 0; ktl < 4; ++ktl)
#pragma unroll
        for (int r = 0; r < 4; ++r) {
          float p = __expf(s[ktl][r] - m_run[qt][r]);
          s[ktl][r] = p;
          lsum[r] += p;
        }
#pragma unroll
      for (int r = 0; r < 4; ++r) {
#pragma unroll
        for (int off = 1; off < 16; off <<= 1)
          lsum[r] += __shfl_xor(lsum[r], off);
        l_run[qt][r] = l_run[qt][r] * alpha[r] + lsum[r];
      }
#pragma unroll
      for (int dt = 0; dt < 4; ++dt)
#pragma unroll
        for (int r = 0; r < 4; ++r) O[qt][dt][r] *= alpha[r];
#pragma unroll
      for (int ktl = 0; ktl < 4; ++ktl)
#pragma unroll
        for (int r = 0; r < 4; ++r)
          Ps[(w * 32 + qt * 16 + quad * 4 + r) * AST + ktl * 16 + l15] =
              (bf16_t)s[ktl][r];

      bf16x8 ap0 = *reinterpret_cast<const bf16x8*>(
          &Ps[(w * 32 + qt * 16 + l15) * AST + quad * 8]);
      bf16x8 ap1 = *reinterpret_cast<const bf16x8*>(
          &Ps[(w * 32 + qt * 16 + l15) * AST + 32 + quad * 8]);
#pragma unroll
      for (int dt = 0; dt < 4; ++dt) {
        O[qt][dt] = __builtin_amdgcn_mfma_f32_16x16x32_bf16(ap0, bv[dt][0],
                                                            O[qt][dt], 0, 0, 0);
        O[qt][dt] = __builtin_amdgcn_mfma_f32_16x16x32_bf16(ap1, bv[dt][1],
                                                            O[qt][dt], 0, 0, 0);
      }
    }
  }

#pragma unroll
  for (int qt = 0; qt < 2; ++qt) {
    float inv[4];
#pragma unroll
    for (int r = 0; r < 4; ++r) inv[r] = 1.0f / l_run[qt][r];
#pragma unroll
    for (int dt = 0; dt < 4; ++dt)
#pragma unroll
      for (int r = 0; r < 4; ++r)
        out_b[(size_t)(qg0 + w * 32 + qt * 16 + quad * 4 + r) * DIM +
              h * 64 + dt * 16 + l15] = O[qt][dt][r] * inv[r];
  }
}

// ---------------------------------------------------------------------------
// out = LayerNorm(a + b) * g + beta (row = 1024, eps 1e-5). a generic dtype.
// Alias-safe in place (per-thread read-before-write).
// ---------------------------------------------------------------------------
template <typename TA>
__global__ __launch_bounds__(256) void add_ln_k(const TA* a,
                                                const float* b,
                                                const float* __restrict__ g,
                                                const float* __restrict__ be,
                                                float* out) {
  const int row = blockIdx.x;
  const int t   = threadIdx.x;
  const size_t base = (size_t)row * DIM;

  float x[4];
  {
    floatx4 bv = *reinterpret_cast<const floatx4*>(b + base + t * 4);
    if constexpr (sizeof(TA) == 2) {
      bf16x4 av = *reinterpret_cast<const bf16x4*>(a + base + t * 4);
#pragma unroll
      for (int i = 0; i < 4; ++i) x[i] = (float)av[i] + bv[i];
    } else {
      floatx4 av = *reinterpret_cast<const floatx4*>(a + base + t * 4);
#pragma unroll
      for (int i = 0; i < 4; ++i) x[i] = av[i] + bv[i];
    }
  }
  float s1 = 0.0f, s2 = 0.0f;
#pragma unroll
  for (int i = 0; i < 4; ++i) { s1 += x[i]; s2 += x[i] * x[i]; }
#pragma unroll
  for (int off = 32; off; off >>= 1) {
    s1 += __shfl_xor(s1, off);
    s2 += __shfl_xor(s2, off);
  }
  __shared__ float ls1[4], ls2[4];
  if ((t & 63) == 0) { ls1[t >> 6] = s1; ls2[t >> 6] = s2; }
  __syncthreads();
  float S1 = ls1[0] + ls1[1] + ls1[2] + ls1[3];
  float S2 = ls2[0] + ls2[1] + ls2[2] + ls2[3];
  float mu  = S1 * (1.0f / DIM);
  float var = S2 * (1.0f / DIM) - mu * mu;
  float rs  = rsqrtf(var + 1e-5f);
#pragma unroll
  for (int i = 0; i < 4; ++i) {
    int c = t * 4 + i;
    out[base + c] = (x[i] - mu) * rs * g[c] + be[c];
  }
}

// ---------------------------------------------------------------------------
extern "C" void kernel_launch(void* const* d_in, const int* in_sizes, int n_in,
                              void* d_out, int out_size, void* d_ws, size_t ws_size,
                              hipStream_t stream) {
  const float* x   = (const float*)d_in[0];
  const float* Wq  = (const float*)d_in[1];
  const float* Wk  = (const float*)d_in[2];
  const float* Wv  = (const float*)d_in[3];
  const float* bq  = (const float*)d_in[4];
  const float* bk  = (const float*)d_in[5];
  const float* bv  = (const float*)d_in[6];
  const float* g1  = (const float*)d_in[7];
  const float* be1 = (const float*)d_in[8];
  const float* W1  = (const float*)d_in[9];
  const float* b1  = (const float*)d_in[10];
  const float* W2  = (const float*)d_in[11];
  const float* b2  = (const float*)d_in[12];
  const float* g2  = (const float*)d_in[13];
  const float* be2 = (const float*)d_in[14];
  float* out = (float*)d_out;
  char*  ws  = (char*)d_ws;

  // ws layout (bytes), peak 38 MiB (<= 48 MiB proven safe):
  //   phase 1: WqkvT [0, 6291456)          3072 x 1024 bf16 (Wq|Wk|Wv ^T)
  //            qkv2  [6291456, 31457280)   4096 x 3072 bf16 (per batch-pair)
  //            vt    [31457280, 39845888)  32 x 64 x 2048 bf16
  //   phase 2: W1Tq  [0, 2097152)          1024 x 1024 bf16 (hidden quarter)
  //            W2Tq  [2097152, 4194304)    1024 x 1024 bf16
  //            mid   [4194304, 20971520)   8192 x 1024 bf16
  //            ffnO  [20971520, 37748736)  8192 x 1024 bf16 (accumulated)
  bf16_t* WqkvT = (bf16_t*)(ws);
  bf16_t* qkv2  = (bf16_t*)(ws + 6291456);
  bf16_t* vt    = (bf16_t*)(ws + 31457280);
  bf16_t* W1Tq  = (bf16_t*)(ws);
  bf16_t* W2Tq  = (bf16_t*)(ws + 2097152);
  bf16_t* mid   = (bf16_t*)(ws + 4194304);
  bf16_t* ffnO  = (bf16_t*)(ws + 20971520);

  dim3 tb(32, 8);
  // --- weight transposes (f32 -> bf16 NxK) ---
  convT<<<dim3(32, 32), tb, 0, stream>>>(Wq, 1024, WqkvT,           1024);
  convT<<<dim3(32, 32), tb, 0, stream>>>(Wk, 1024, WqkvT + 1048576, 1024);
  convT<<<dim3(32, 32), tb, 0, stream>>>(Wv, 1024, WqkvT + 2097152, 1024);

  // --- QKV + attention, per batch-pair ---
  for (int p = 0; p < 2; ++p) {
    const float* xp   = x   + (size_t)p * 2 * S_LEN * DIM;
    float*       outp = out + (size_t)p * 2 * S_LEN * DIM;
    gemm_abt<float><<<dim3(8, 32, 3), 256, 0, stream>>>(
        xp, 1024, WqkvT, 1024, qkv2, 3072, 1024, bq, bk, bv, 1024, 0, 0);
    transpose_v<<<dim3(64, 2, 32), tb, 0, stream>>>(qkv2, vt);
    attn_mfma<<<dim3(16, 16, 2), 256, 0, stream>>>(qkv2, vt, outp);
  }
  // h = LN(attn + x), in place in d_out
  add_ln_k<float><<<8192, 256, 0, stream>>>(out, x, g1, be1, out);

  // --- FFN in 4 hidden-quarters at full M=8192 ---
  for (int q = 0; q < 4; ++q) {
    convT<<<dim3(32, 32), tb, 0, stream>>>(W1 + q * 1024, 4096, W1Tq, 1024);
    convT<<<dim3(32, 32), tb, 0, stream>>>(W2 + (size_t)q * 1024 * 1024, 1024, W2Tq, 1024);
    gemm_abt<float><<<dim3(8, 64, 1), 256, 0, stream>>>(
        out, 1024, W1Tq, 0, mid, 1024, 0, b1 + q * 1024, nullptr, nullptr,
        1024, 1, 0);
    gemm_abt<bf16_t><<<dim3(8, 64, 1), 256, 0, stream>>>(
        mid, 1024, W2Tq, 0, ffnO, 1024, 0, (q == 0) ? b2 : nullptr, nullptr,
        nullptr, 1024, 0, (q > 0) ? 1 : 0);
  }
  // out = LN(ffn + h), in place (h = d_out)
  add_ln_k<bf16_t><<<8192, 256, 0, stream>>>(ffnO, out, g2, be2, out);
}

// Round 8
// 823.271 us; speedup vs baseline: 4.5268x; 1.0547x over previous
//
#include <hip/hip_runtime.h>
#include <hip/hip_bf16.h>

typedef __bf16 bf16_t;
typedef __bf16 bf16x8 __attribute__((ext_vector_type(8)));
typedef __bf16 bf16x4 __attribute__((ext_vector_type(4)));
typedef float  floatx4 __attribute__((ext_vector_type(4)));

#define DIM    1024
#define S_LEN  2048
#define NHEAD  16

// ---------------------------------------------------------------------------
// load 8 consecutive elements as bf16x8 (f32 source converts, bf16 is a copy)
// ---------------------------------------------------------------------------
template <typename T>
__device__ __forceinline__ bf16x8 load8bf(const T* src) {
  if constexpr (sizeof(T) == 2) {
    return *reinterpret_cast<const bf16x8*>(src);
  } else {
    floatx4 f0 = *reinterpret_cast<const floatx4*>(src);
    floatx4 f1 = *reinterpret_cast<const floatx4*>(src + 4);
    bf16x8 h;
    h[0] = (bf16_t)f0[0]; h[1] = (bf16_t)f0[1];
    h[2] = (bf16_t)f0[2]; h[3] = (bf16_t)f0[3];
    h[4] = (bf16_t)f1[0]; h[5] = (bf16_t)f1[1];
    h[6] = (bf16_t)f1[2]; h[7] = (bf16_t)f1[3];
    return h;
  }
}

// ---------------------------------------------------------------------------
// Weight transpose+convert, f32 KxN -> bf16 NxK. z selects among up to 3
// (in, ldi, out) triples (pass repeats for unused slots; grid.z trims).
// ---------------------------------------------------------------------------
__global__ __launch_bounds__(256) void convT3(
    const float* __restrict__ in0, int ldi0, bf16_t* __restrict__ out0,
    const float* __restrict__ in1, int ldi1, bf16_t* __restrict__ out1,
    const float* __restrict__ in2, int ldi2, bf16_t* __restrict__ out2,
    int ldo) {
  __shared__ bf16_t tile[32][33];
  const int z = blockIdx.z;
  const float* in = (z == 0) ? in0 : ((z == 1) ? in1 : in2);
  bf16_t* out = (z == 0) ? out0 : ((z == 1) ? out1 : out2);
  int ldi = (z == 0) ? ldi0 : ((z == 1) ? ldi1 : ldi2);
  int tx = threadIdx.x, ty = threadIdx.y;
  int n0 = blockIdx.x * 32, k0 = blockIdx.y * 32;
#pragma unroll
  for (int i = 0; i < 4; ++i)
    tile[ty + 8 * i][tx] = (bf16_t)in[(size_t)(k0 + ty + 8 * i) * ldi + n0 + tx];
  __syncthreads();
#pragma unroll
  for (int i = 0; i < 4; ++i)
    out[(size_t)(n0 + ty + 8 * i) * ldo + k0 + tx] = tile[tx][ty + 8 * i];
}

// ---------------------------------------------------------------------------
// GEMM: C(MxN) = A(MxK) @ Bt(NxK)^T + bias; optional ReLU / bf16-accumulate.
// A f32 or bf16 (converted during staging); Bt pre-transposed bf16 (ldbt=K).
// blockIdx.z: Bt row offset z*zBRow, C col offset z*zCOff, bias selection.
// 128x128 tile, BK=32, 4 waves, 4x4 MFMA. Verified gfx950 layouts.
// ---------------------------------------------------------------------------
#define BM 128
#define BN 128
#define BK 32
#define LSTR 40  // 32+8 pad: 80B row stride (16B multiple), 2-way bank = free

template <typename TA>
__global__ __launch_bounds__(256) void gemm_abt(
    const TA* __restrict__ A, int lda,
    const bf16_t* __restrict__ Bt, int zBRow,
    bf16_t* __restrict__ C, int ldc, int zCOff,
    const float* __restrict__ bias0, const float* __restrict__ bias1,
    const float* __restrict__ bias2,
    int K, int relu, int accum) {
  __shared__ bf16_t As[BM * LSTR];
  __shared__ bf16_t Bs[BN * LSTR];
  const int z = blockIdx.z;
  const float* bias = (z == 0) ? bias0 : ((z == 1) ? bias1 : bias2);
  const bf16_t* Bz = Bt + (size_t)z * zBRow * K;
  C += (size_t)z * zCOff;

  const int tid  = threadIdx.x;
  const int lane = tid & 63;
  const int wave = tid >> 6;
  const int wr   = wave >> 1;
  const int wc   = wave & 1;
  const int quad = lane >> 4;
  const int l15  = lane & 15;
  const int m0   = blockIdx.y * BM;
  const int n0   = blockIdx.x * BN;

  floatx4 acc[4][4];
#pragma unroll
  for (int i = 0; i < 4; ++i)
#pragma unroll
    for (int j = 0; j < 4; ++j) acc[i][j] = (floatx4)(0.0f);

  const int kIters = K / BK;
  for (int kt = 0; kt < kIters; ++kt) {
#pragma unroll
    for (int p = 0; p < 2; ++p) {
      int id  = p * 256 + tid;
      int row = id >> 2;
      int c8  = (id & 3) * 8;
      *reinterpret_cast<bf16x8*>(&As[row * LSTR + c8]) =
          load8bf(A + (size_t)(m0 + row) * lda + kt * BK + c8);
      *reinterpret_cast<bf16x8*>(&Bs[row * LSTR + c8]) =
          *reinterpret_cast<const bf16x8*>(Bz + (size_t)(n0 + row) * K + kt * BK + c8);
    }
    __syncthreads();

    bf16x8 a[4], b[4];
#pragma unroll
    for (int i = 0; i < 4; ++i)
      a[i] = *reinterpret_cast<const bf16x8*>(&As[(wr * 64 + i * 16 + l15) * LSTR + quad * 8]);
#pragma unroll
    for (int j = 0; j < 4; ++j)
      b[j] = *reinterpret_cast<const bf16x8*>(&Bs[(wc * 64 + j * 16 + l15) * LSTR + quad * 8]);
#pragma unroll
    for (int i = 0; i < 4; ++i)
#pragma unroll
      for (int j = 0; j < 4; ++j)
        acc[i][j] = __builtin_amdgcn_mfma_f32_16x16x32_bf16(a[i], b[j], acc[i][j], 0, 0, 0);
    __syncthreads();
  }

#pragma unroll
  for (int j = 0; j < 4; ++j) {
    int gn = n0 + wc * 64 + j * 16 + l15;
    float bv = bias ? bias[gn] : 0.0f;
#pragma unroll
    for (int i = 0; i < 4; ++i) {
      int gm = m0 + wr * 64 + i * 16 + quad * 4;
#pragma unroll
      for (int r = 0; r < 4; ++r) {
        float v = acc[i][j][r] + bv;
        if (relu) v = fmaxf(v, 0.0f);
        size_t idx = (size_t)(gm + r) * ldc + gn;
        if (accum) v += (float)C[idx];
        C[idx] = (bf16_t)v;
      }
    }
  }
}

// ---------------------------------------------------------------------------
// V transpose: per (pair-local batch z, head h), V slice [2048 s][64 d] from
// qkv2 (col offset 2048+h*64, row stride 3072) -> vt[bh][64 d][2048 s].
// ---------------------------------------------------------------------------
__global__ __launch_bounds__(256) void transpose_v(const bf16_t* __restrict__ in,
                                                   bf16_t* __restrict__ outp) {
  __shared__ bf16_t tile[32][33];
  int tx = threadIdx.x, ty = threadIdx.y;
  int s0 = blockIdx.x * 32, d0 = blockIdx.y * 32, bh = blockIdx.z;
  int z = bh >> 4, h = bh & 15;
  const bf16_t* src = in + (size_t)z * S_LEN * 3072 + 2048 + h * 64;
#pragma unroll
  for (int i = 0; i < 4; ++i)
    tile[ty + 8 * i][tx] = src[(size_t)(s0 + ty + 8 * i) * 3072 + d0 + tx];
  __syncthreads();
  bf16_t* dst = outp + (size_t)bh * 64 * S_LEN;
#pragma unroll
  for (int i = 0; i < 4; ++i)
    dst[(size_t)(d0 + ty + 8 * i) * S_LEN + s0 + tx] = tile[tx][ty + 8 * i];
}

// ---------------------------------------------------------------------------
// Paired MFMA flash attention, causal, scale 1/dph folded into Q staging.
// Block = q-tile pair {pi, 15-pi} x one (z,h): work = (2pi+2)+(32-2pi) = 34
// K-tiles, constant across blocks (perfect balance; grid 8x16x2 = 256 = 1
// block/CU). K/V staged once per pair (64 MFMA per 16KB stage). QsPs buffer:
// Q staging for tile A then tile B, then reused as the P scratch (wave-
// private rows; per-wave LDS ops are in-order -> no extra barriers).
// ---------------------------------------------------------------------------
#define TQ  128
#define TK  64
#define AST 72  // LDS row stride bf16: 144B (16B mult), b128 reads 2-way = free

__global__ __launch_bounds__(256, 1) void attn_mfma2(
    const bf16_t* __restrict__ qkv, const bf16_t* __restrict__ vt,
    float* __restrict__ out) {
  __shared__ bf16_t QsPs[TQ * AST];
  __shared__ bf16_t Ks[TK * AST];
  __shared__ bf16_t Vs[TK * AST];  // V^T tile: [d][key]

  const int tid  = threadIdx.x;
  const int lane = tid & 63;
  const int w    = tid >> 6;
  const int quad = lane >> 4;
  const int l15  = lane & 15;
  const int pi   = blockIdx.x;        // 0..7
  const int h    = blockIdx.y;
  const int z    = blockIdx.z;
  const int qb[2] = {pi, 15 - pi};
  const bf16_t* qkv_b = qkv + (size_t)z * S_LEN * 3072;
  const bf16_t* vt_bh = vt + ((size_t)z * NHEAD + h) * 64 * S_LEN;
  float* out_b = out + (size_t)z * S_LEN * DIM;

  // stage Q for both tiles (sequentially through QsPs), keep fragments
  bf16x8 aq[2][2][2];  // [tile][qt][ks]
  for (int tile = 0; tile < 2; ++tile) {
    if (tile) __syncthreads();  // all frag reads of tile0 done before overwrite
    const int qg0 = qb[tile] * TQ;
#pragma unroll
    for (int p = 0; p < 4; ++p) {
      int id  = p * 256 + tid;
      int row = id >> 3;
      int c8  = (id & 7) * 8;
      bf16x8 v = *reinterpret_cast<const bf16x8*>(
          qkv_b + (size_t)(qg0 + row) * 3072 + h * 64 + c8);
      bf16x8 o;
#pragma unroll
      for (int e = 0; e < 8; ++e) o[e] = (bf16_t)((float)v[e] * 0.015625f);
      *reinterpret_cast<bf16x8*>(&QsPs[row * AST + c8]) = o;
    }
    __syncthreads();
#pragma unroll
    for (int qt = 0; qt < 2; ++qt)
#pragma unroll
      for (int ks = 0; ks < 2; ++ks)
        aq[tile][qt][ks] = *reinterpret_cast<const bf16x8*>(
            &QsPs[(w * 32 + qt * 16 + l15) * AST + ks * 32 + quad * 8]);
  }

  float m_run[2][2][4], l_run[2][2][4];
  floatx4 O[2][2][4];
#pragma unroll
  for (int t = 0; t < 2; ++t)
#pragma unroll
    for (int qt = 0; qt < 2; ++qt)
#pragma unroll
      for (int r = 0; r < 4; ++r) {
        m_run[t][qt][r] = -1e30f; l_run[t][qt][r] = 0.0f;
      }
#pragma unroll
  for (int t = 0; t < 2; ++t)
#pragma unroll
    for (int qt = 0; qt < 2; ++qt)
#pragma unroll
      for (int dt = 0; dt < 4; ++dt) O[t][qt][dt] = (floatx4)(0.0f);

  const int ktEnd = 2 * (qb[1] + 1);  // tile B bound (tile A skips via mask test)
  for (int kt = 0; kt < ktEnd; ++kt) {
    __syncthreads();  // prior-iter K/V readers done (kt=0: frag reads done)
#pragma unroll
    for (int p = 0; p < 2; ++p) {
      int id  = p * 256 + tid;
      int row = id >> 3;
      int c8  = (id & 7) * 8;
      *reinterpret_cast<bf16x8*>(&Ks[row * AST + c8]) =
          *reinterpret_cast<const bf16x8*>(
              qkv_b + (size_t)(kt * TK + row) * 3072 + 1024 + h * 64 + c8);
      *reinterpret_cast<bf16x8*>(&Vs[row * AST + c8]) =
          *reinterpret_cast<const bf16x8*>(
              vt_bh + (size_t)row * S_LEN + kt * TK + c8);
    }
    __syncthreads();

    // shared K and V^T fragments for this K-tile
    bf16x8 bk[4][2], bv[4][2];
#pragma unroll
    for (int i = 0; i < 4; ++i)
#pragma unroll
      for (int ks = 0; ks < 2; ++ks) {
        bk[i][ks] = *reinterpret_cast<const bf16x8*>(
            &Ks[(i * 16 + l15) * AST + ks * 32 + quad * 8]);
        bv[i][ks] = *reinterpret_cast<const bf16x8*>(
            &Vs[(i * 16 + l15) * AST + ks * 32 + quad * 8]);
      }

#pragma unroll
    for (int tile = 0; tile < 2; ++tile) {
      const int qg0 = qb[tile] * TQ;
#pragma unroll
      for (int qt = 0; qt < 2; ++qt) {
        const int qtb = qg0 + w * 32 + qt * 16;
        if (kt * TK > qtb + 15) continue;  // fully above diagonal: skip

        floatx4 s[4];
#pragma unroll
        for (int ktl = 0; ktl < 4; ++ktl) {
          s[ktl] = __builtin_amdgcn_mfma_f32_16x16x32_bf16(
              aq[tile][qt][0], bk[ktl][0], (floatx4)(0.0f), 0, 0, 0);
          s[ktl] = __builtin_amdgcn_mfma_f32_16x16x32_bf16(
              aq[tile][qt][1], bk[ktl][1], s[ktl], 0, 0, 0);
        }
        if (kt * TK + TK - 1 > qtb) {
#pragma unroll
          for (int ktl = 0; ktl < 4; ++ktl) {
            int gk = kt * TK + ktl * 16 + l15;
#pragma unroll
            for (int r = 0; r < 4; ++r) {
              int gq = qtb + quad * 4 + r;
              if (gk > gq) s[ktl][r] = -1e30f;
            }
          }
        }
        float lsum[4], alpha[4];
#pragma unroll
        for (int r = 0; r < 4; ++r) {
          float mv = fmaxf(fmaxf(s[0][r], s[1][r]), fmaxf(s[2][r], s[3][r]));
#pragma unroll
          for (int off = 1; off < 16; off <<= 1)
            mv = fmaxf(mv, __shfl_xor(mv, off));
          float mn = fmaxf(m_run[tile][qt][r], mv);
          alpha[r] = __expf(m_run[tile][qt][r] - mn);
          m_run[tile][qt][r] = mn;
          lsum[r] = 0.0f;
        }
#pragma unroll
        for (int ktl = 0; ktl < 4; ++ktl)
#pragma unroll
          for (int r = 0; r < 4; ++r) {
            float p = __expf(s[ktl][r] - m_run[tile][qt][r]);
            s[ktl][r] = p;
            lsum[r] += p;
          }
#pragma unroll
        for (int r = 0; r < 4; ++r) {
#pragma unroll
          for (int off = 1; off < 16; off <<= 1)
            lsum[r] += __shfl_xor(lsum[r], off);
          l_run[tile][qt][r] = l_run[tile][qt][r] * alpha[r] + lsum[r];
        }
#pragma unroll
        for (int dt = 0; dt < 4; ++dt)
#pragma unroll
          for (int r = 0; r < 4; ++r) O[tile][qt][dt][r] *= alpha[r];
        // P -> LDS (wave-private rows of QsPs; in-order per-wave LDS)
#pragma unroll
        for (int ktl = 0; ktl < 4; ++ktl)
#pragma unroll
          for (int r = 0; r < 4; ++r)
            QsPs[(w * 32 + qt * 16 + quad * 4 + r) * AST + ktl * 16 + l15] =
                (bf16_t)s[ktl][r];

        bf16x8 ap0 = *reinterpret_cast<const bf16x8*>(
            &QsPs[(w * 32 + qt * 16 + l15) * AST + quad * 8]);
        bf16x8 ap1 = *reinterpret_cast<const bf16x8*>(
            &QsPs[(w * 32 + qt * 16 + l15) * AST + 32 + quad * 8]);
#pragma unroll
        for (int dt = 0; dt < 4; ++dt) {
          O[tile][qt][dt] = __builtin_amdgcn_mfma_f32_16x16x32_bf16(
              ap0, bv[dt][0], O[tile][qt][dt], 0, 0, 0);
          O[tile][qt][dt] = __builtin_amdgcn_mfma_f32_16x16x32_bf16(
              ap1, bv[dt][1], O[tile][qt][dt], 0, 0, 0);
        }
      }
    }
  }

  // epilogue: O / l -> out (f32), both tiles
#pragma unroll
  for (int tile = 0; tile < 2; ++tile) {
    const int qg0 = qb[tile] * TQ;
#pragma unroll
    for (int qt = 0; qt < 2; ++qt) {
      float inv[4];
#pragma unroll
      for (int r = 0; r < 4; ++r) inv[r] = 1.0f / l_run[tile][qt][r];
#pragma unroll
      for (int dt = 0; dt < 4; ++dt)
#pragma unroll
        for (int r = 0; r < 4; ++r)
          out_b[(size_t)(qg0 + w * 32 + qt * 16 + quad * 4 + r) * DIM +
                h * 64 + dt * 16 + l15] = O[tile][qt][dt][r] * inv[r];
    }
  }
}

// ---------------------------------------------------------------------------
// out = LayerNorm(a + b) * g + beta (row = 1024, eps 1e-5). a generic dtype.
// Alias-safe in place (per-thread read-before-write).
// ---------------------------------------------------------------------------
template <typename TA>
__global__ __launch_bounds__(256) void add_ln_k(const TA* a,
                                                const float* b,
                                                const float* __restrict__ g,
                                                const float* __restrict__ be,
                                                float* out) {
  const int row = blockIdx.x;
  const int t   = threadIdx.x;
  const size_t base = (size_t)row * DIM;

  float x[4];
  {
    floatx4 bv = *reinterpret_cast<const floatx4*>(b + base + t * 4);
    if constexpr (sizeof(TA) == 2) {
      bf16x4 av = *reinterpret_cast<const bf16x4*>(a + base + t * 4);
#pragma unroll
      for (int i = 0; i < 4; ++i) x[i] = (float)av[i] + bv[i];
    } else {
      floatx4 av = *reinterpret_cast<const floatx4*>(a + base + t * 4);
#pragma unroll
      for (int i = 0; i < 4; ++i) x[i] = av[i] + bv[i];
    }
  }
  float s1 = 0.0f, s2 = 0.0f;
#pragma unroll
  for (int i = 0; i < 4; ++i) { s1 += x[i]; s2 += x[i] * x[i]; }
#pragma unroll
  for (int off = 32; off; off >>= 1) {
    s1 += __shfl_xor(s1, off);
    s2 += __shfl_xor(s2, off);
  }
  __shared__ float ls1[4], ls2[4];
  if ((t & 63) == 0) { ls1[t >> 6] = s1; ls2[t >> 6] = s2; }
  __syncthreads();
  float S1 = ls1[0] + ls1[1] + ls1[2] + ls1[3];
  float S2 = ls2[0] + ls2[1] + ls2[2] + ls2[3];
  float mu  = S1 * (1.0f / DIM);
  float var = S2 * (1.0f / DIM) - mu * mu;
  float rs  = rsqrtf(var + 1e-5f);
#pragma unroll
  for (int i = 0; i < 4; ++i) {
    int c = t * 4 + i;
    out[base + c] = (x[i] - mu) * rs * g[c] + be[c];
  }
}

// ---------------------------------------------------------------------------
extern "C" void kernel_launch(void* const* d_in, const int* in_sizes, int n_in,
                              void* d_out, int out_size, void* d_ws, size_t ws_size,
                              hipStream_t stream) {
  const float* x   = (const float*)d_in[0];
  const float* Wq  = (const float*)d_in[1];
  const float* Wk  = (const float*)d_in[2];
  const float* Wv  = (const float*)d_in[3];
  const float* bq  = (const float*)d_in[4];
  const float* bk  = (const float*)d_in[5];
  const float* bv  = (const float*)d_in[6];
  const float* g1  = (const float*)d_in[7];
  const float* be1 = (const float*)d_in[8];
  const float* W1  = (const float*)d_in[9];
  const float* b1  = (const float*)d_in[10];
  const float* W2  = (const float*)d_in[11];
  const float* b2  = (const float*)d_in[12];
  const float* g2  = (const float*)d_in[13];
  const float* be2 = (const float*)d_in[14];
  float* out = (float*)d_out;
  char*  ws  = (char*)d_ws;

  // ws layout (bytes), peak 38 MiB (proven safe):
  //   phase 1: WqkvT [0, 6291456)          3072 x 1024 bf16 (Wq|Wk|Wv ^T)
  //            qkv2  [6291456, 31457280)   4096 x 3072 bf16 (per batch-pair)
  //            vt    [31457280, 39845888)  32 x 64 x 2048 bf16
  //   phase 2: W1Tq  [0, 2097152)          1024 x 1024 bf16 (hidden quarter)
  //            W2Tq  [2097152, 4194304)    1024 x 1024 bf16
  //            mid   [4194304, 20971520)   8192 x 1024 bf16
  //            ffnO  [20971520, 37748736)  8192 x 1024 bf16 (accumulated)
  bf16_t* WqkvT = (bf16_t*)(ws);
  bf16_t* qkv2  = (bf16_t*)(ws + 6291456);
  bf16_t* vt    = (bf16_t*)(ws + 31457280);
  bf16_t* W1Tq  = (bf16_t*)(ws);
  bf16_t* W2Tq  = (bf16_t*)(ws + 2097152);
  bf16_t* mid   = (bf16_t*)(ws + 4194304);
  bf16_t* ffnO  = (bf16_t*)(ws + 20971520);

  dim3 tb(32, 8);
  // --- weight transposes (f32 -> bf16 NxK), one fused dispatch ---
  convT3<<<dim3(32, 32, 3), tb, 0, stream>>>(
      Wq, 1024, WqkvT, Wk, 1024, WqkvT + 1048576, Wv, 1024, WqkvT + 2097152, 1024);

  // --- QKV + attention, per batch-pair ---
  for (int p = 0; p < 2; ++p) {
    const float* xp   = x   + (size_t)p * 2 * S_LEN * DIM;
    float*       outp = out + (size_t)p * 2 * S_LEN * DIM;
    gemm_abt<float><<<dim3(8, 32, 3), 256, 0, stream>>>(
        xp, 1024, WqkvT, 1024, qkv2, 3072, 1024, bq, bk, bv, 1024, 0, 0);
    transpose_v<<<dim3(64, 2, 32), tb, 0, stream>>>(qkv2, vt);
    attn_mfma2<<<dim3(8, 16, 2), 256, 0, stream>>>(qkv2, vt, outp);
  }
  // h = LN(attn + x), in place in d_out
  add_ln_k<float><<<8192, 256, 0, stream>>>(out, x, g1, be1, out);

  // --- FFN in 4 hidden-quarters at full M=8192 ---
  for (int q = 0; q < 4; ++q) {
    convT3<<<dim3(32, 32, 2), tb, 0, stream>>>(
        W1 + q * 1024, 4096, W1Tq,
        W2 + (size_t)q * 1024 * 1024, 1024, W2Tq,
        nullptr, 0, nullptr, 1024);
    gemm_abt<float><<<dim3(8, 64, 1), 256, 0, stream>>>(
        out, 1024, W1Tq, 0, mid, 1024, 0, b1 + q * 1024, nullptr, nullptr,
        1024, 1, 0);
    gemm_abt<bf16_t><<<dim3(8, 64, 1), 256, 0, stream>>>(
        mid, 1024, W2Tq, 0, ffnO, 1024, 0, (q == 0) ? b2 : nullptr, nullptr,
        nullptr, 1024, 0, (q > 0) ? 1 : 0);
  }
  // out = LN(ffn + h), in place (h = d_out)
  add_ln_k<bf16_t><<<8192, 256, 0, stream>>>(ffnO, out, g2, be2, out);
}